// Round 3
// baseline (596.460 us; speedup 1.0000x reference)
//
#include <hip/hip_runtime.h>
#include <hip/hip_bf16.h>

typedef __attribute__((ext_vector_type(8))) short bf16x8;   // 8 bf16 in 4 VGPRs
typedef __attribute__((ext_vector_type(4))) float f32x4;

#define DMODEL 1024
#define SEQ    2048
#define NB     2
#define NH     16
#define HD     64
#define FDIM   4096
#define NTOK   (NB*SEQ)   // 4096

// ---------------- transpose + f32->bf16 convert: src[R][C] f32 -> dst[C][R] bf16 ----------------
__global__ __launch_bounds__(256) void transpose_cvt_k(const float* __restrict__ src,
                                                       __hip_bfloat16* __restrict__ dst,
                                                       int R, int C) {
    __shared__ __hip_bfloat16 tile[32][33];
    int tx = threadIdx.x, ty = threadIdx.y;
    int bx = blockIdx.x * 32, by = blockIdx.y * 32;
    for (int i = 0; i < 32; i += 8)
        tile[ty + i][tx] = __float2bfloat16(src[(size_t)(by + ty + i) * C + bx + tx]);
    __syncthreads();
    for (int i = 0; i < 32; i += 8)
        dst[(size_t)(bx + ty + i) * R + by + tx] = tile[tx][ty + i];
}

// ---------------- layernorm: f32 row of 1024, unbiased std (ddof=1), /(std+eps) -> bf16 ----------------
__global__ __launch_bounds__(256) void ln_kernel(const float* __restrict__ x,
                                                 const float* __restrict__ alpha,
                                                 const float* __restrict__ beta,
                                                 __hip_bfloat16* __restrict__ out) {
    const int row = blockIdx.x, tid = threadIdx.x;
    const size_t base = (size_t)row * DMODEL;
    float v[4];
    for (int e = 0; e < 4; ++e) v[e] = x[base + tid * 4 + e];
    float s1 = v[0] + v[1] + v[2] + v[3];
    float s2 = v[0]*v[0] + v[1]*v[1] + v[2]*v[2] + v[3]*v[3];
    for (int off = 32; off > 0; off >>= 1) {
        s1 += __shfl_down(s1, off);
        s2 += __shfl_down(s2, off);
    }
    __shared__ float red[8];
    int w = tid >> 6, lane = tid & 63;
    if (lane == 0) { red[w * 2] = s1; red[w * 2 + 1] = s2; }
    __syncthreads();
    if (tid == 0) {
        float a = 0.f, b = 0.f;
        for (int i = 0; i < 4; ++i) { a += red[2 * i]; b += red[2 * i + 1]; }
        red[0] = a; red[1] = b;
    }
    __syncthreads();
    s1 = red[0]; s2 = red[1];
    float mean = s1 * (1.0f / DMODEL);
    float var  = fmaxf((s2 - (float)DMODEL * mean * mean) * (1.0f / (DMODEL - 1)), 0.f);
    float inv  = 1.0f / (sqrtf(var) + 1e-6f);
    for (int e = 0; e < 4; ++e) {
        int c = tid * 4 + e;
        float y = alpha[c] * (v[e] - mean) * inv + beta[c];
        out[base + c] = __float2bfloat16(y);
    }
}

// ---------------- GEMM: C[M][N] = A[M][K](bf16) @ Bt[N][K]^T(bf16) + bias(f32) ----------------
// EPI: 0 = bias -> bf16 ; 1 = bias+relu -> bf16 ; 2 = bias + f32 residual -> f32
template <int EPI>
__global__ __launch_bounds__(256) void gemm_bt(const __hip_bfloat16* __restrict__ A,
                                               const __hip_bfloat16* __restrict__ Bt,
                                               const float* __restrict__ bias,
                                               const float* __restrict__ res,
                                               void* __restrict__ Cout,
                                               int M, int N, int K) {
    __shared__ alignas(16) __hip_bfloat16 As[128 * 32];
    __shared__ alignas(16) __hip_bfloat16 Bs[128 * 32];
    const int tid = threadIdx.x, l = tid & 63;
    const int w = tid >> 6;
    const int wm = w >> 1, wn = w & 1, quad = l >> 4, lc = l & 15;
    const int row0 = blockIdx.y * 128, col0 = blockIdx.x * 128;

    const int sr0 = tid >> 2,         sc0 = (tid & 3) * 8;
    const int sr1 = (tid + 256) >> 2, sc1 = ((tid + 256) & 3) * 8;

    f32x4 acc[4][4];
    for (int i = 0; i < 4; ++i)
        for (int j = 0; j < 4; ++j) acc[i][j] = (f32x4){0.f, 0.f, 0.f, 0.f};

    for (int k0 = 0; k0 < K; k0 += 32) {
        bf16x8 a0 = *(const bf16x8*)&A [(size_t)(row0 + sr0) * K + k0 + sc0];
        bf16x8 a1 = *(const bf16x8*)&A [(size_t)(row0 + sr1) * K + k0 + sc1];
        bf16x8 b0 = *(const bf16x8*)&Bt[(size_t)(col0 + sr0) * K + k0 + sc0];
        bf16x8 b1 = *(const bf16x8*)&Bt[(size_t)(col0 + sr1) * K + k0 + sc1];
        __syncthreads();
        *(bf16x8*)&As[sr0 * 32 + sc0] = a0;
        *(bf16x8*)&As[sr1 * 32 + sc1] = a1;
        *(bf16x8*)&Bs[sr0 * 32 + sc0] = b0;
        *(bf16x8*)&Bs[sr1 * 32 + sc1] = b1;
        __syncthreads();
        bf16x8 af[4], bfr[4];
        for (int i = 0; i < 4; ++i) af[i]  = *(const bf16x8*)&As[(64 * wm + 16 * i + lc) * 32 + quad * 8];
        for (int j = 0; j < 4; ++j) bfr[j] = *(const bf16x8*)&Bs[(64 * wn + 16 * j + lc) * 32 + quad * 8];
        for (int i = 0; i < 4; ++i)
            for (int j = 0; j < 4; ++j)
                acc[i][j] = __builtin_amdgcn_mfma_f32_16x16x32_bf16(af[i], bfr[j], acc[i][j], 0, 0, 0);
    }

    __hip_bfloat16* Cb = (__hip_bfloat16*)Cout;
    float* Cf = (float*)Cout;
    for (int j = 0; j < 4; ++j) {
        int col = col0 + 64 * wn + 16 * j + lc;
        float bv = bias[col];
        for (int i = 0; i < 4; ++i) {
            int rbase = row0 + 64 * wm + 16 * i + quad * 4;
            for (int r = 0; r < 4; ++r) {
                size_t idx = (size_t)(rbase + r) * N + col;
                float vacc = acc[i][j][r] + bv;
                if (EPI == 0)      Cb[idx] = __float2bfloat16(vacc);
                else if (EPI == 1) Cb[idx] = __float2bfloat16(fmaxf(vacc, 0.f));
                else               Cf[idx] = vacc + res[idx];
            }
        }
    }
}

// ---------------- flash attention: per (b,h), 64-row Q tiles, 64-key K/V tiles ----------------
__global__ __launch_bounds__(256) void attn_kernel(const __hip_bfloat16* __restrict__ q,
                                                   const __hip_bfloat16* __restrict__ k,
                                                   const __hip_bfloat16* __restrict__ v,
                                                   const int* __restrict__ mask,
                                                   __hip_bfloat16* __restrict__ ctx) {
    const int qt = blockIdx.x, bh = blockIdx.y;
    const int b = bh >> 4, h = bh & 15;
    const int q0 = qt * 64;
    const int tid = threadIdx.x, w = tid >> 6, l = tid & 63, quad = l >> 4, lc = l & 15;

    __shared__ alignas(16) __hip_bfloat16 Qs[64 * 64];
    __shared__ alignas(16) __hip_bfloat16 Ks[64 * 64];
    __shared__ alignas(16) __hip_bfloat16 Vt[64 * 64];   // [d][k]
    __shared__ alignas(16) __hip_bfloat16 Ps[4][16 * 64];
    __shared__ int maskS[64];

    const size_t base = (size_t)b * SEQ * DMODEL + (size_t)h * HD;

    for (int c = tid; c < 512; c += 256) {
        int r = c >> 3, dcol = (c & 7) * 8;
        *(bf16x8*)&Qs[r * 64 + dcol] = *(const bf16x8*)&q[base + (size_t)(q0 + r) * DMODEL + dcol];
    }
    __syncthreads();
    bf16x8 qf0 = *(const bf16x8*)&Qs[(w * 16 + lc) * 64 + quad * 8];
    bf16x8 qf1 = *(const bf16x8*)&Qs[(w * 16 + lc) * 64 + 32 + quad * 8];

    f32x4 o[4];
    for (int dj = 0; dj < 4; ++dj) o[dj] = (f32x4){0.f, 0.f, 0.f, 0.f};
    float m_r[4], l_r[4];
    for (int r = 0; r < 4; ++r) { m_r[r] = -1e30f; l_r[r] = 0.f; }

    for (int kt = 0; kt < SEQ / 64; ++kt) {
        const int k0 = kt * 64;
        __syncthreads();
        for (int c = tid; c < 512; c += 256) {
            int r = c >> 3, dcol = (c & 7) * 8;
            *(bf16x8*)&Ks[r * 64 + dcol] = *(const bf16x8*)&k[base + (size_t)(k0 + r) * DMODEL + dcol];
            union { bf16x8 v8; short s[8]; } u;
            u.v8 = *(const bf16x8*)&v[base + (size_t)(k0 + r) * DMODEL + dcol];
            for (int e = 0; e < 8; ++e) ((short*)Vt)[(dcol + e) * 64 + r] = u.s[e];
        }
        if (tid < 64) maskS[tid] = mask[b * SEQ + k0 + tid];
        __syncthreads();

        // S = Q K^T / 8, C-layout: row=quad*4+r, col=jn*16+lc
        f32x4 sa[4];
        for (int jn = 0; jn < 4; ++jn) {
            f32x4 z = (f32x4){0.f, 0.f, 0.f, 0.f};
            bf16x8 kf0 = *(const bf16x8*)&Ks[(jn * 16 + lc) * 64 + quad * 8];
            bf16x8 kf1 = *(const bf16x8*)&Ks[(jn * 16 + lc) * 64 + 32 + quad * 8];
            z = __builtin_amdgcn_mfma_f32_16x16x32_bf16(qf0, kf0, z, 0, 0, 0);
            z = __builtin_amdgcn_mfma_f32_16x16x32_bf16(qf1, kf1, z, 0, 0, 0);
            sa[jn] = z;
        }
        for (int jn = 0; jn < 4; ++jn) {
            int mc = maskS[jn * 16 + lc];
            for (int r = 0; r < 4; ++r) {
                float s = sa[jn][r] * 0.125f;
                sa[jn][r] = (mc == 0) ? -1e9f : s;
            }
        }
        // online softmax per row (rows owned by 16-lane quad groups)
        float alpha[4], p[4][4];
        for (int r = 0; r < 4; ++r) {
            float mx = fmaxf(fmaxf(sa[0][r], sa[1][r]), fmaxf(sa[2][r], sa[3][r]));
            for (int off = 1; off < 16; off <<= 1) mx = fmaxf(mx, __shfl_xor(mx, off, 16));
            float mn = fmaxf(m_r[r], mx);
            alpha[r] = __expf(m_r[r] - mn);
            float rs = 0.f;
            for (int jn = 0; jn < 4; ++jn) { p[jn][r] = __expf(sa[jn][r] - mn); rs += p[jn][r]; }
            for (int off = 1; off < 16; off <<= 1) rs += __shfl_xor(rs, off, 16);
            l_r[r] = l_r[r] * alpha[r] + rs;
            m_r[r] = mn;
        }
        for (int dj = 0; dj < 4; ++dj)
            for (int r = 0; r < 4; ++r) o[dj][r] *= alpha[r];
        // P: C-layout -> LDS -> A-layout
        for (int jn = 0; jn < 4; ++jn)
            for (int r = 0; r < 4; ++r)
                Ps[w][(quad * 4 + r) * 64 + jn * 16 + lc] = __float2bfloat16(p[jn][r]);
        __syncthreads();
        bf16x8 pf0 = *(const bf16x8*)&Ps[w][lc * 64 + quad * 8];
        bf16x8 pf1 = *(const bf16x8*)&Ps[w][lc * 64 + 32 + quad * 8];
        for (int dj = 0; dj < 4; ++dj) {
            bf16x8 vf0 = *(const bf16x8*)&Vt[(dj * 16 + lc) * 64 + quad * 8];
            bf16x8 vf1 = *(const bf16x8*)&Vt[(dj * 16 + lc) * 64 + 32 + quad * 8];
            o[dj] = __builtin_amdgcn_mfma_f32_16x16x32_bf16(pf0, vf0, o[dj], 0, 0, 0);
            o[dj] = __builtin_amdgcn_mfma_f32_16x16x32_bf16(pf1, vf1, o[dj], 0, 0, 0);
        }
    }

    for (int r = 0; r < 4; ++r) {
        float invl = 1.0f / l_r[r];
        int row = q0 + w * 16 + quad * 4 + r;
        for (int dj = 0; dj < 4; ++dj)
            ctx[base + (size_t)row * DMODEL + dj * 16 + lc] = __float2bfloat16(o[dj][r] * invl);
    }
}

// ---------------- launcher ----------------
extern "C" void kernel_launch(void* const* d_in, const int* in_sizes, int n_in,
                              void* d_out, int out_size, void* d_ws, size_t ws_size,
                              hipStream_t stream) {
    const float* x    = (const float*)d_in[0];
    const int*   mask = (const int*)d_in[1];
    const float* wq = (const float*)d_in[2];
    const float* bq = (const float*)d_in[3];
    const float* wk = (const float*)d_in[4];
    const float* bk = (const float*)d_in[5];
    const float* wv = (const float*)d_in[6];
    const float* bv = (const float*)d_in[7];
    const float* wo = (const float*)d_in[8];
    const float* bo = (const float*)d_in[9];
    const float* ln1_a = (const float*)d_in[10];
    const float* ln1_b = (const float*)d_in[11];
    const float* ln2_a = (const float*)d_in[12];
    const float* ln2_b = (const float*)d_in[13];
    const float* w1 = (const float*)d_in[14];
    const float* b1 = (const float*)d_in[15];
    const float* w2 = (const float*)d_in[16];
    const float* b2 = (const float*)d_in[17];
    float* out = (float*)d_out;

    char* ws = (char*)d_ws;
    const size_t SZ_WT  = (size_t)DMODEL * DMODEL * 2;   // 2 MB bf16
    const size_t SZ_ACT = (size_t)NTOK * DMODEL * 2;     // 8 MB bf16
    const size_t SZ_WF  = (size_t)FDIM * DMODEL * 2;     // 8 MB bf16
    size_t off = 0;
    __hip_bfloat16* wqT = (__hip_bfloat16*)(ws + off); off += SZ_WT;
    __hip_bfloat16* wkT = (__hip_bfloat16*)(ws + off); off += SZ_WT;
    __hip_bfloat16* wvT = (__hip_bfloat16*)(ws + off); off += SZ_WT;
    __hip_bfloat16* woT = (__hip_bfloat16*)(ws + off); off += SZ_WT;
    __hip_bfloat16* w1T = (__hip_bfloat16*)(ws + off); off += SZ_WF;  // [F][D]
    __hip_bfloat16* w2T = (__hip_bfloat16*)(ws + off); off += SZ_WF;  // [D][F]
    __hip_bfloat16* h1  = (__hip_bfloat16*)(ws + off); off += SZ_ACT;
    __hip_bfloat16* qb  = (__hip_bfloat16*)(ws + off); off += SZ_ACT;
    __hip_bfloat16* kb  = (__hip_bfloat16*)(ws + off); off += SZ_ACT;
    __hip_bfloat16* vb  = (__hip_bfloat16*)(ws + off); off += SZ_ACT;
    __hip_bfloat16* ctx = (__hip_bfloat16*)(ws + off); off += SZ_ACT;
    float*          x1  = (float*)(ws + off);          off += (size_t)NTOK * DMODEL * 4;
    __hip_bfloat16* h2  = (__hip_bfloat16*)(ws + off); off += SZ_ACT;
    __hip_bfloat16* ff1 = h1;  // reuse h1..vb region (32 MB bf16) after attention

    dim3 tb(32, 8);
    transpose_cvt_k<<<dim3(32, 32), tb, 0, stream>>>(wq, wqT, DMODEL, DMODEL);
    transpose_cvt_k<<<dim3(32, 32), tb, 0, stream>>>(wk, wkT, DMODEL, DMODEL);
    transpose_cvt_k<<<dim3(32, 32), tb, 0, stream>>>(wv, wvT, DMODEL, DMODEL);
    transpose_cvt_k<<<dim3(32, 32), tb, 0, stream>>>(wo, woT, DMODEL, DMODEL);
    transpose_cvt_k<<<dim3(128, 32), tb, 0, stream>>>(w1, w1T, DMODEL, FDIM);
    transpose_cvt_k<<<dim3(32, 128), tb, 0, stream>>>(w2, w2T, FDIM, DMODEL);

    ln_kernel<<<NTOK, 256, 0, stream>>>(x, ln1_a, ln1_b, h1);

    gemm_bt<0><<<dim3(DMODEL / 128, NTOK / 128), 256, 0, stream>>>(h1, wqT, bq, nullptr, qb, NTOK, DMODEL, DMODEL);
    gemm_bt<0><<<dim3(DMODEL / 128, NTOK / 128), 256, 0, stream>>>(h1, wkT, bk, nullptr, kb, NTOK, DMODEL, DMODEL);
    gemm_bt<0><<<dim3(DMODEL / 128, NTOK / 128), 256, 0, stream>>>(h1, wvT, bv, nullptr, vb, NTOK, DMODEL, DMODEL);

    attn_kernel<<<dim3(SEQ / 64, NB * NH), 256, 0, stream>>>(qb, kb, vb, mask, ctx);

    gemm_bt<2><<<dim3(DMODEL / 128, NTOK / 128), 256, 0, stream>>>(ctx, woT, bo, x, x1, NTOK, DMODEL, DMODEL);

    ln_kernel<<<NTOK, 256, 0, stream>>>(x1, ln2_a, ln2_b, h2);

    gemm_bt<1><<<dim3(FDIM / 128, NTOK / 128), 256, 0, stream>>>(h2, w1T, b1, nullptr, ff1, NTOK, FDIM, DMODEL);
    gemm_bt<2><<<dim3(DMODEL / 128, NTOK / 128), 256, 0, stream>>>(ff1, w2T, b2, x1, out, NTOK, DMODEL, FDIM);
}

// Round 4
// 566.065 us; speedup vs baseline: 1.0537x; 1.0537x over previous
//
#include <hip/hip_runtime.h>
#include <hip/hip_bf16.h>

typedef __attribute__((ext_vector_type(8))) short bf16x8;   // 8 bf16 in 4 VGPRs
typedef __attribute__((ext_vector_type(4))) float f32x4;
typedef unsigned int uint32;
typedef unsigned short ushort16;

#define DMODEL 1024
#define SEQ    2048
#define NB     2
#define NH     16
#define HD     64
#define FDIM   4096
#define NTOK   (NB*SEQ)   // 4096

// ---------------- async global->LDS (wave-uniform LDS base + lane*16) ----------------
__device__ __forceinline__ void async16(const void* g, void* s) {
    __builtin_amdgcn_global_load_lds((const __attribute__((address_space(1))) unsigned int*)g,
                                     (__attribute__((address_space(3))) unsigned int*)s,
                                     16, 0, 0);
}

// ---------------- transpose + f32->bf16 convert: src[R][C] f32 -> dst[C][R] bf16 ----------------
__global__ __launch_bounds__(256) void transpose_cvt_k(const float* __restrict__ src,
                                                       __hip_bfloat16* __restrict__ dst,
                                                       int R, int C) {
    __shared__ __hip_bfloat16 tile[32][33];
    int tx = threadIdx.x, ty = threadIdx.y;
    int bx = blockIdx.x * 32, by = blockIdx.y * 32;
    for (int i = 0; i < 32; i += 8)
        tile[ty + i][tx] = __float2bfloat16(src[(size_t)(by + ty + i) * C + bx + tx]);
    __syncthreads();
    for (int i = 0; i < 32; i += 8)
        dst[(size_t)(bx + ty + i) * R + by + tx] = tile[tx][ty + i];
}

// ---------------- layernorm: f32 row of 1024, unbiased std (ddof=1), /(std+eps) -> bf16 ----------------
__global__ __launch_bounds__(256) void ln_kernel(const float* __restrict__ x,
                                                 const float* __restrict__ alpha,
                                                 const float* __restrict__ beta,
                                                 __hip_bfloat16* __restrict__ out) {
    const int row = blockIdx.x, tid = threadIdx.x;
    const size_t base = (size_t)row * DMODEL;
    float v[4];
    for (int e = 0; e < 4; ++e) v[e] = x[base + tid * 4 + e];
    float s1 = v[0] + v[1] + v[2] + v[3];
    float s2 = v[0]*v[0] + v[1]*v[1] + v[2]*v[2] + v[3]*v[3];
    for (int off = 32; off > 0; off >>= 1) {
        s1 += __shfl_down(s1, off);
        s2 += __shfl_down(s2, off);
    }
    __shared__ float red[8];
    int w = tid >> 6, lane = tid & 63;
    if (lane == 0) { red[w * 2] = s1; red[w * 2 + 1] = s2; }
    __syncthreads();
    if (tid == 0) {
        float a = 0.f, b = 0.f;
        for (int i = 0; i < 4; ++i) { a += red[2 * i]; b += red[2 * i + 1]; }
        red[0] = a; red[1] = b;
    }
    __syncthreads();
    s1 = red[0]; s2 = red[1];
    float mean = s1 * (1.0f / DMODEL);
    float var  = fmaxf((s2 - (float)DMODEL * mean * mean) * (1.0f / (DMODEL - 1)), 0.f);
    float inv  = 1.0f / (sqrtf(var) + 1e-6f);
    for (int e = 0; e < 4; ++e) {
        int c = tid * 4 + e;
        float y = alpha[c] * (v[e] - mean) * inv + beta[c];
        out[base + c] = __float2bfloat16(y);
    }
}

// ---------------- GEMM: C[M][N] = A[M][K](bf16) @ Bt[N][K]^T(bf16) + bias(f32) ----------------
// EPI: 0 = bias -> bf16 ; 1 = bias+relu -> bf16 ; 2 = bias + f32 residual -> f32
// Staging: global_load_lds width=16 (m97 pattern). LDS layout must stay lane-contiguous.
template <int EPI>
__global__ __launch_bounds__(256) void gemm_bt(const __hip_bfloat16* __restrict__ A,
                                               const __hip_bfloat16* __restrict__ Bt,
                                               const float* __restrict__ bias,
                                               const float* __restrict__ res,
                                               void* __restrict__ Cout,
                                               int M, int N, int K) {
    __shared__ alignas(16) __hip_bfloat16 As[128 * 32];
    __shared__ alignas(16) __hip_bfloat16 Bs[128 * 32];
    const int tid = threadIdx.x, l = tid & 63;
    const int w = tid >> 6;
    const int wm = w >> 1, wn = w & 1, quad = l >> 4, lc = l & 15;
    const int row0 = blockIdx.y * 128, col0 = blockIdx.x * 128;

    f32x4 acc[4][4];
    for (int i = 0; i < 4; ++i)
        for (int j = 0; j < 4; ++j) acc[i][j] = (f32x4){0.f, 0.f, 0.f, 0.f};

    for (int k0 = 0; k0 < K; k0 += 32) {
        __syncthreads();   // previous iteration's LDS reads complete
        for (int c = 0; c < 2; ++c) {
            const __hip_bfloat16* pa = A  + (size_t)(row0 + 32 * w + 16 * c + (l >> 2)) * K + k0 + (l & 3) * 8;
            const __hip_bfloat16* pb = Bt + (size_t)(col0 + 32 * w + 16 * c + (l >> 2)) * K + k0 + (l & 3) * 8;
            async16(pa, (char*)As + w * 2048 + c * 1024);
            async16(pb, (char*)Bs + w * 2048 + c * 1024);
        }
        __syncthreads();   // staging visible to all
        bf16x8 af[4], bfr[4];
        for (int i = 0; i < 4; ++i) af[i]  = *(const bf16x8*)&As[(64 * wm + 16 * i + lc) * 32 + quad * 8];
        for (int j = 0; j < 4; ++j) bfr[j] = *(const bf16x8*)&Bs[(64 * wn + 16 * j + lc) * 32 + quad * 8];
        for (int i = 0; i < 4; ++i)
            for (int j = 0; j < 4; ++j)
                acc[i][j] = __builtin_amdgcn_mfma_f32_16x16x32_bf16(af[i], bfr[j], acc[i][j], 0, 0, 0);
    }

    __hip_bfloat16* Cb = (__hip_bfloat16*)Cout;
    float* Cf = (float*)Cout;
    for (int j = 0; j < 4; ++j) {
        int col = col0 + 64 * wn + 16 * j + lc;
        float bv = bias[col];
        for (int i = 0; i < 4; ++i) {
            int rbase = row0 + 64 * wm + 16 * i + quad * 4;
            for (int r = 0; r < 4; ++r) {
                size_t idx = (size_t)(rbase + r) * N + col;
                float vacc = acc[i][j][r] + bv;
                if (EPI == 0)      Cb[idx] = __float2bfloat16(vacc);
                else if (EPI == 1) Cb[idx] = __float2bfloat16(fmaxf(vacc, 0.f));
                else               Cf[idx] = vacc + res[idx];
            }
        }
    }
}

// ---------------- flash attention, LDS-conflict-free version ----------------
// Q,K fragments load straight from global (natural MFMA A/B layouts).
// V transposed into LDS with stride-33-dword rows (bank = (d+t)%32 / (lc+4q+j)%32: 2-way, free).
// P round-trip through per-wave stride-66-short tiles.
__global__ __launch_bounds__(256) void attn_kernel(const __hip_bfloat16* __restrict__ q,
                                                   const __hip_bfloat16* __restrict__ k,
                                                   const __hip_bfloat16* __restrict__ v,
                                                   const int* __restrict__ mask,
                                                   __hip_bfloat16* __restrict__ ctx) {
    const int qt = blockIdx.x, bh = blockIdx.y;
    const int b = bh >> 4, h = bh & 15;
    const int q0 = qt * 64;
    const int tid = threadIdx.x, w = tid >> 6, l = tid & 63, quad = l >> 4, lc = l & 15;

    __shared__ uint32 Vt32[64 * 33];      // V^T pairs: [d][t], t = k/2, row stride 33 dwords
    __shared__ uint32 Ps32[4][16 * 33];   // per-wave P tile: [m][33] dwords (66 shorts)
    __shared__ int maskS[64];

    const size_t base = (size_t)b * SEQ * DMODEL + (size_t)h * HD;

    // Q A-fragments straight from global: m = w*16+lc, k = quad*8+j (+32)
    const __hip_bfloat16* qrow = &q[base + (size_t)(q0 + w * 16 + lc) * DMODEL];
    bf16x8 qf0 = *(const bf16x8*)&qrow[quad * 8];
    bf16x8 qf1 = *(const bf16x8*)&qrow[32 + quad * 8];

    f32x4 o[4];
    for (int dj = 0; dj < 4; ++dj) o[dj] = (f32x4){0.f, 0.f, 0.f, 0.f};
    float m_r[4], l_r[4];
    for (int r = 0; r < 4; ++r) { m_r[r] = -1e30f; l_r[r] = 0.f; }

    for (int kt = 0; kt < SEQ / 64; ++kt) {
        const int k0 = kt * 64;
        __syncthreads();   // protect Vt from previous iteration's reads
        // ---- stage V transposed: lane pair (r, r^1) builds k-pairs via shuffle ----
        for (int c = tid; c < 512; c += 256) {
            int r = c >> 3, dcol = (c & 7) * 8;
            union { bf16x8 v8; uint32 u[4]; ushort16 s[8]; } u;
            u.v8 = *(const bf16x8*)&v[base + (size_t)(k0 + r) * DMODEL + dcol];
            // even r sends its high-d half (s4..7); odd r sends low-d half (s0..3)
            uint32 s0 = (r & 1) ? u.u[0] : u.u[2];
            uint32 s1 = (r & 1) ? u.u[1] : u.u[3];
            uint32 r0 = __shfl_xor(s0, 8);
            uint32 r1 = __shfl_xor(s1, 8);
            ushort16 rs[4] = { (ushort16)(r0 & 0xffff), (ushort16)(r0 >> 16),
                               (ushort16)(r1 & 0xffff), (ushort16)(r1 >> 16) };
            int t = r >> 1;
            if (!(r & 1)) {
                for (int i = 0; i < 4; ++i) {
                    uint32 pack = (uint32)(ushort16)u.s[i] | ((uint32)rs[i] << 16);
                    Vt32[(dcol + i) * 33 + t] = pack;
                }
            } else {
                for (int i = 0; i < 4; ++i) {
                    uint32 pack = (uint32)rs[i] | ((uint32)(ushort16)u.s[4 + i] << 16);
                    Vt32[(dcol + 4 + i) * 33 + t] = pack;
                }
            }
        }
        if (tid < 64) maskS[tid] = mask[b * SEQ + k0 + tid];
        __syncthreads();

        // ---- S = Q K^T / 8 : K B-fragments straight from global ----
        f32x4 sa[4];
        for (int jn = 0; jn < 4; ++jn) {
            const __hip_bfloat16* krow = &k[base + (size_t)(k0 + jn * 16 + lc) * DMODEL];
            bf16x8 kf0 = *(const bf16x8*)&krow[quad * 8];
            bf16x8 kf1 = *(const bf16x8*)&krow[32 + quad * 8];
            f32x4 z = (f32x4){0.f, 0.f, 0.f, 0.f};
            z = __builtin_amdgcn_mfma_f32_16x16x32_bf16(qf0, kf0, z, 0, 0, 0);
            z = __builtin_amdgcn_mfma_f32_16x16x32_bf16(qf1, kf1, z, 0, 0, 0);
            sa[jn] = z;
        }
        for (int jn = 0; jn < 4; ++jn) {
            int mc = maskS[jn * 16 + lc];
            for (int r = 0; r < 4; ++r) {
                float s = sa[jn][r] * 0.125f;
                sa[jn][r] = (mc == 0) ? -1e9f : s;
            }
        }
        // ---- online softmax (rows owned by 16-lane quad groups) ----
        float alpha[4], p[4][4];
        for (int r = 0; r < 4; ++r) {
            float mx = fmaxf(fmaxf(sa[0][r], sa[1][r]), fmaxf(sa[2][r], sa[3][r]));
            for (int off = 1; off < 16; off <<= 1) mx = fmaxf(mx, __shfl_xor(mx, off, 16));
            float mn = fmaxf(m_r[r], mx);
            alpha[r] = __expf(m_r[r] - mn);
            float rs = 0.f;
            for (int jn = 0; jn < 4; ++jn) { p[jn][r] = __expf(sa[jn][r] - mn); rs += p[jn][r]; }
            for (int off = 1; off < 16; off <<= 1) rs += __shfl_xor(rs, off, 16);
            l_r[r] = l_r[r] * alpha[r] + rs;
            m_r[r] = mn;
        }
        for (int dj = 0; dj < 4; ++dj)
            for (int r = 0; r < 4; ++r) o[dj][r] *= alpha[r];
        // ---- P: C-layout -> per-wave LDS tile (stride 66 shorts) -> A-layout ----
        ushort16* psw = (ushort16*)&Ps32[w][0];
        for (int jn = 0; jn < 4; ++jn)
            for (int r = 0; r < 4; ++r) {
                __hip_bfloat16 hb = __float2bfloat16(p[jn][r]);
                psw[(quad * 4 + r) * 66 + jn * 16 + lc] = *(ushort16*)&hb;
            }
        __syncthreads_count(0);  // no-op barrier avoided; per-wave tile needs only lgkmcnt (compiler handles)
        union { uint32 u[4]; bf16x8 v8; } pf0, pf1;
        for (int j = 0; j < 4; ++j) {
            pf0.u[j] = Ps32[w][lc * 33 + quad * 4 + j];
            pf1.u[j] = Ps32[w][lc * 33 + 16 + quad * 4 + j];
        }
        for (int dj = 0; dj < 4; ++dj) {
            union { uint32 u[4]; bf16x8 v8; } vf0, vf1;
            int vbase = (dj * 16 + lc) * 33 + quad * 4;
            for (int j = 0; j < 4; ++j) {
                vf0.u[j] = Vt32[vbase + j];
                vf1.u[j] = Vt32[vbase + 16 + j];
            }
            o[dj] = __builtin_amdgcn_mfma_f32_16x16x32_bf16(pf0.v8, vf0.v8, o[dj], 0, 0, 0);
            o[dj] = __builtin_amdgcn_mfma_f32_16x16x32_bf16(pf1.v8, vf1.v8, o[dj], 0, 0, 0);
        }
    }

    for (int r = 0; r < 4; ++r) {
        float invl = 1.0f / l_r[r];
        int row = q0 + w * 16 + quad * 4 + r;
        for (int dj = 0; dj < 4; ++dj)
            ctx[base + (size_t)row * DMODEL + dj * 16 + lc] = __float2bfloat16(o[dj][r] * invl);
    }
}

// ---------------- launcher ----------------
extern "C" void kernel_launch(void* const* d_in, const int* in_sizes, int n_in,
                              void* d_out, int out_size, void* d_ws, size_t ws_size,
                              hipStream_t stream) {
    const float* x    = (const float*)d_in[0];
    const int*   mask = (const int*)d_in[1];
    const float* wq = (const float*)d_in[2];
    const float* bq = (const float*)d_in[3];
    const float* wk = (const float*)d_in[4];
    const float* bk = (const float*)d_in[5];
    const float* wv = (const float*)d_in[6];
    const float* bv = (const float*)d_in[7];
    const float* wo = (const float*)d_in[8];
    const float* bo = (const float*)d_in[9];
    const float* ln1_a = (const float*)d_in[10];
    const float* ln1_b = (const float*)d_in[11];
    const float* ln2_a = (const float*)d_in[12];
    const float* ln2_b = (const float*)d_in[13];
    const float* w1 = (const float*)d_in[14];
    const float* b1 = (const float*)d_in[15];
    const float* w2 = (const float*)d_in[16];
    const float* b2 = (const float*)d_in[17];
    float* out = (float*)d_out;

    char* ws = (char*)d_ws;
    const size_t SZ_WT  = (size_t)DMODEL * DMODEL * 2;   // 2 MB bf16
    const size_t SZ_ACT = (size_t)NTOK * DMODEL * 2;     // 8 MB bf16
    const size_t SZ_WF  = (size_t)FDIM * DMODEL * 2;     // 8 MB bf16
    size_t off = 0;
    __hip_bfloat16* wqT = (__hip_bfloat16*)(ws + off); off += SZ_WT;
    __hip_bfloat16* wkT = (__hip_bfloat16*)(ws + off); off += SZ_WT;
    __hip_bfloat16* wvT = (__hip_bfloat16*)(ws + off); off += SZ_WT;
    __hip_bfloat16* woT = (__hip_bfloat16*)(ws + off); off += SZ_WT;
    __hip_bfloat16* w1T = (__hip_bfloat16*)(ws + off); off += SZ_WF;  // [F][D]
    __hip_bfloat16* w2T = (__hip_bfloat16*)(ws + off); off += SZ_WF;  // [D][F]
    __hip_bfloat16* h1  = (__hip_bfloat16*)(ws + off); off += SZ_ACT;
    __hip_bfloat16* qb  = (__hip_bfloat16*)(ws + off); off += SZ_ACT;
    __hip_bfloat16* kb  = (__hip_bfloat16*)(ws + off); off += SZ_ACT;
    __hip_bfloat16* vb  = (__hip_bfloat16*)(ws + off); off += SZ_ACT;
    __hip_bfloat16* ctx = (__hip_bfloat16*)(ws + off); off += SZ_ACT;
    float*          x1  = (float*)(ws + off);          off += (size_t)NTOK * DMODEL * 4;
    __hip_bfloat16* h2  = (__hip_bfloat16*)(ws + off); off += SZ_ACT;
    __hip_bfloat16* ff1 = h1;  // reuse h1 region after attention

    dim3 tb(32, 8);
    transpose_cvt_k<<<dim3(32, 32), tb, 0, stream>>>(wq, wqT, DMODEL, DMODEL);
    transpose_cvt_k<<<dim3(32, 32), tb, 0, stream>>>(wk, wkT, DMODEL, DMODEL);
    transpose_cvt_k<<<dim3(32, 32), tb, 0, stream>>>(wv, wvT, DMODEL, DMODEL);
    transpose_cvt_k<<<dim3(32, 32), tb, 0, stream>>>(wo, woT, DMODEL, DMODEL);
    transpose_cvt_k<<<dim3(128, 32), tb, 0, stream>>>(w1, w1T, DMODEL, FDIM);
    transpose_cvt_k<<<dim3(32, 128), tb, 0, stream>>>(w2, w2T, FDIM, DMODEL);

    ln_kernel<<<NTOK, 256, 0, stream>>>(x, ln1_a, ln1_b, h1);

    gemm_bt<0><<<dim3(DMODEL / 128, NTOK / 128), 256, 0, stream>>>(h1, wqT, bq, nullptr, qb, NTOK, DMODEL, DMODEL);
    gemm_bt<0><<<dim3(DMODEL / 128, NTOK / 128), 256, 0, stream>>>(h1, wkT, bk, nullptr, kb, NTOK, DMODEL, DMODEL);
    gemm_bt<0><<<dim3(DMODEL / 128, NTOK / 128), 256, 0, stream>>>(h1, wvT, bv, nullptr, vb, NTOK, DMODEL, DMODEL);

    attn_kernel<<<dim3(SEQ / 64, NB * NH), 256, 0, stream>>>(qb, kb, vb, mask, ctx);

    gemm_bt<2><<<dim3(DMODEL / 128, NTOK / 128), 256, 0, stream>>>(ctx, woT, bo, x, x1, NTOK, DMODEL, DMODEL);

    ln_kernel<<<NTOK, 256, 0, stream>>>(x1, ln2_a, ln2_b, h2);

    gemm_bt<1><<<dim3(FDIM / 128, NTOK / 128), 256, 0, stream>>>(h2, w1T, b1, nullptr, ff1, NTOK, FDIM, DMODEL);
    gemm_bt<2><<<dim3(DMODEL / 128, NTOK / 128), 256, 0, stream>>>(ff1, w2T, b2, x1, out, NTOK, DMODEL, FDIM);
}